// Round 2
// baseline (98.603 us; speedup 1.0000x reference)
//
#include <hip/hip_runtime.h>
#include <hip/hip_bf16.h>

typedef __attribute__((ext_vector_type(8))) short short8v;
typedef __attribute__((ext_vector_type(4))) float f32x4;

static constexpr int B_ = 4, S_ = 2048, E_ = 768, H_ = 12, D_ = 64;
static constexpr int NROWS = B_ * H_ * S_;       // 98304
static constexpr float LOG2E = 1.44269504088896340736f;
static constexpr float LN2 = 0.69314718055994530942f;

typedef __attribute__((address_space(3))) unsigned int lds_u32;
typedef const __attribute__((address_space(1))) unsigned int glb_u32;

__device__ __forceinline__ void gload16(const void* g, void* l) {
  __builtin_amdgcn_global_load_lds((glb_u32*)g, (lds_u32*)l, 16, 0, 0);
}

__device__ __forceinline__ unsigned short f2bf(float f) {
  union { float f; unsigned int u; } v; v.f = f;
  unsigned int u = v.u;
  unsigned int r = (u + 0x7fffu + ((u >> 16) & 1u)) >> 16;
  return (unsigned short)r;
}

__global__ __launch_bounds__(256) void cvt_x_kernel(const float4* __restrict__ x,
                                                    ushort4* __restrict__ xb, int n4) {
  int i = blockIdx.x * 256 + threadIdx.x;
  if (i >= n4) return;
  float4 v = x[i];
  ushort4 o;
  o.x = f2bf(v.x); o.y = f2bf(v.y); o.z = f2bf(v.z); o.w = f2bf(v.w);
  xb[i] = o;
}

// wb[1536][768]: rows 0..767 = beta[h]*log2e*W^Q; rows 768..1535 = W^K
__global__ __launch_bounds__(256) void cvt_w_kernel(const float4* __restrict__ wq,
                                                    const float4* __restrict__ wk,
                                                    const float* __restrict__ beta,
                                                    ushort4* __restrict__ wb, int n4) {
  int i = blockIdx.x * 256 + threadIdx.x;
  if (i < n4) {
    int row = i / (E_ / 4);
    float sc = beta[row >> 6] * LOG2E;
    float4 v = wq[i];
    ushort4 o;
    o.x = f2bf(v.x * sc); o.y = f2bf(v.y * sc); o.z = f2bf(v.z * sc); o.w = f2bf(v.w * sc);
    wb[i] = o;
  } else if (i < 2 * n4) {
    int j = i - n4;
    float4 v = wk[j];
    ushort4 o;
    o.x = f2bf(v.x); o.y = f2bf(v.y); o.z = f2bf(v.z); o.w = f2bf(v.w);
    wb[i] = o;
  }
}

// GEMM: C[8192,1536] = X[8192,768] * W[1536,768]^T, 128x128 tile, BK=32.
__global__ __launch_bounds__(256) void proj_kernel(const unsigned short* __restrict__ xb,
                                                   const unsigned short* __restrict__ wb,
                                                   unsigned short* __restrict__ Qb,
                                                   unsigned short* __restrict__ Kb) {
  __shared__ unsigned short lA[128 * 32];
  __shared__ unsigned short lB[128 * 32];
  const int mt = blockIdx.x, nt = blockIdx.y;
  const int t = threadIdx.x;
  const int wid = t >> 6, lane = t & 63, l15 = lane & 15, lhi = lane >> 4;
  const int wr = (wid >> 1) * 64, wc = (wid & 1) * 64;

  f32x4 acc[4][4] = {};

  const int row = t >> 2, ch = t & 3;
  const unsigned short* gA = xb + (size_t)(mt * 128 + row) * E_ + ch * 8;
  const unsigned short* gB = wb + (size_t)(nt * 128 + row) * E_ + ch * 8;

  for (int k0 = 0; k0 < E_; k0 += 32) {
    gload16(gA + k0, &lA[t * 8]);
    gload16(gA + (size_t)64 * E_ + k0, &lA[2048 + t * 8]);
    gload16(gB + k0, &lB[t * 8]);
    gload16(gB + (size_t)64 * E_ + k0, &lB[2048 + t * 8]);
    __syncthreads();
    short8v aF[4], bF[4];
#pragma unroll
    for (int m = 0; m < 4; ++m)
      aF[m] = *(const short8v*)&lA[(wr + m * 16 + l15) * 32 + lhi * 8];
#pragma unroll
    for (int n = 0; n < 4; ++n)
      bF[n] = *(const short8v*)&lB[(wc + n * 16 + l15) * 32 + lhi * 8];
#pragma unroll
    for (int m = 0; m < 4; ++m)
#pragma unroll
      for (int n = 0; n < 4; ++n)
        acc[m][n] = __builtin_amdgcn_mfma_f32_16x16x32_bf16(aF[m], bF[n], acc[m][n], 0, 0, 0);
    __syncthreads();
  }

  const int nbase = nt * 128 + wc;
  unsigned short* dst = (nbase < 768) ? Qb : Kb;
  const int nb = (nbase < 768) ? nbase : nbase - 768;
#pragma unroll
  for (int m = 0; m < 4; ++m)
#pragma unroll
    for (int n = 0; n < 4; ++n)
#pragma unroll
      for (int r = 0; r < 4; ++r) {
        int M = mt * 128 + wr + m * 16 + lhi * 4 + r;
        int col = nb + n * 16 + l15;
        int h = col >> 6, d = col & 63;
        int b = M >> 11, s = M & (S_ - 1);
        dst[((((size_t)b * H_ + h) * S_ + s) << 6) + d] = f2bf(acc[m][n][r]);
      }
}

// --- lse helpers -----------------------------------------------------------

__device__ __forceinline__ void loadKtile(const unsigned short* __restrict__ kp,
                                          int l15, int lhi, short8v kf[4][2]) {
#pragma unroll
  for (int f = 0; f < 4; ++f) {
    const unsigned short* kr = kp + ((f * 16 + l15) << 6) + lhi * 8;
    kf[f][0] = *(const short8v*)kr;
    kf[f][1] = *(const short8v*)(kr + 32);
  }
}

__device__ __forceinline__ void computeTile(const short8v kf[4][2], const short8v q[4][2],
                                            f32x4 sp[4], bool isD, int l15, int lhi) {
#pragma unroll
  for (int rb = 0; rb < 4; ++rb) {
    f32x4 acc[4] = {};
    __builtin_amdgcn_s_setprio(1);
#pragma unroll
    for (int f = 0; f < 4; ++f) {
      acc[f] = __builtin_amdgcn_mfma_f32_16x16x32_bf16(q[rb][0], kf[f][0], acc[f], 0, 0, 0);
      acc[f] = __builtin_amdgcn_mfma_f32_16x16x32_bf16(q[rb][1], kf[f][1], acc[f], 0, 0, 0);
    }
    __builtin_amdgcn_s_setprio(0);
#pragma unroll
    for (int f = 0; f < 4; ++f) {
      f32x4 e;
#pragma unroll
      for (int r = 0; r < 4; ++r) e[r] = __builtin_amdgcn_exp2f(acc[f][r]);
      if (isD && f == rb) {               // self-exclusion: zero diag element
#pragma unroll
        for (int r = 0; r < 4; ++r)
          if (l15 == lhi * 4 + r) e[r] = 0.f;
      }
      sp[rb] += e;                        // v_pk_add_f32 x2
    }
  }
}

// LSE row sums, LDS-free + register double-buffered K prefetch.
// Per-(b,h) K panel (256 KB) is L2-resident (XCD map keeps all 32 blocks of
// one (b,h) on one XCD -> 3 MB working set). Round-1 lesson: direct L2 reads
// WITHOUT prefetch expose ~300cy latency per tile (convoy effect, 17% issue
// util). Fix: one-tile-deep register double buffer (kfA/kfB, static indexing
// via unroll-by-2) -- per-tile compute issue (~530cy: 32 MFMA + 64 exp2)
// covers the next tile's load latency by construction (ILP, not TLP).
__global__ __launch_bounds__(256) void lse_kernel(const unsigned short* __restrict__ Qb,
                                                  const unsigned short* __restrict__ Kb,
                                                  float* __restrict__ rowsum) {
  const int L = blockIdx.x + 8 * (blockIdx.y + 12 * blockIdx.z);  // 0..1535
  const int xcd = L & 7, j = L >> 3;      // hw round-robins wgid%8 -> XCD
  const int split = j & 3;
  const int st = (j >> 2) & 7;
  const int g = xcd + 8 * (j >> 5);       // (b,h) group, 0..47
  const int h = g % H_, b = g / H_;

  const int tid = threadIdx.x;
  const int wid = tid >> 6, lane = tid & 63;
  const int l15 = lane & 15, lhi = lane >> 4;
  const size_t hb = ((size_t)b * H_ + h) * S_;
  const unsigned short* Qbase = Qb + hb * D_;
  const unsigned short* Kbase = Kb + hb * D_;
  const int s0 = st * 256 + wid * 64;     // 64 rows per wave
  const int tb = split * 512;             // 8 tiles of 64

  short8v q[4][2];
#pragma unroll
  for (int rb = 0; rb < 4; ++rb) {
    const unsigned short* qr = Qbase + (size_t)(s0 + rb * 16 + l15) * D_ + lhi * 8;
    q[rb][0] = *(const short8v*)qr;
    q[rb][1] = *(const short8v*)(qr + 32);
  }

  // tile index (within this split's 8 tiles) holding this wave's diagonal
  const int dtile = ((s0 >> 9) == split) ? ((s0 - tb) >> 6) : -1;

  f32x4 sp[4] = {};                       // sp[rb][r] row partial sums
  const unsigned short* kp = Kbase + ((size_t)tb << 6);

  short8v kfA[4][2], kfB[4][2];
  loadKtile(kp, l15, lhi, kfA);           // tile 0

#pragma unroll 1
  for (int i = 0; i < 8; i += 2) {
    loadKtile(kp + (size_t)(i + 1) * 64 * D_, l15, lhi, kfB);   // prefetch i+1
    computeTile(kfA, q, sp, i == dtile, l15, lhi);
    if (i + 2 < 8)
      loadKtile(kp + (size_t)(i + 2) * 64 * D_, l15, lhi, kfA); // prefetch i+2
    computeTile(kfB, q, sp, i + 1 == dtile, l15, lhi);
  }

#pragma unroll
  for (int rb = 0; rb < 4; ++rb)
#pragma unroll
    for (int r = 0; r < 4; ++r) {
      float s = sp[rb][r];
#pragma unroll
      for (int off = 1; off < 16; off <<= 1) s += __shfl_xor(s, off, 64);
      if (l15 == 0)
        rowsum[(size_t)split * NROWS + hb + s0 + rb * 16 + lhi * 4 + r] = s;
    }
}

__global__ __launch_bounds__(256) void finish1_kernel(const float* __restrict__ rowsum,
                                                      const float* __restrict__ beta,
                                                      float* __restrict__ partial) {
  int row = blockIdx.x * 256 + threadIdx.x;
  float s = (rowsum[row] + rowsum[NROWS + row]) +
            (rowsum[2 * NROWS + row] + rowsum[3 * NROWS + row]);
  int h = (row >> 11) % H_;
  float c = __builtin_amdgcn_logf(s) * LN2 / beta[h];   // v_log_f32 = log2
#pragma unroll
  for (int off = 1; off < 64; off <<= 1) c += __shfl_xor(c, off, 64);
  __shared__ float wsum[4];
  int wid = threadIdx.x >> 6;
  if ((threadIdx.x & 63) == 0) wsum[wid] = c;
  __syncthreads();
  if (threadIdx.x == 0) partial[blockIdx.x] = wsum[0] + wsum[1] + wsum[2] + wsum[3];
}

__global__ __launch_bounds__(256) void finish2_kernel(const float* __restrict__ partial, int n,
                                                      float* __restrict__ out) {
  float s = 0.f;
  for (int i = threadIdx.x; i < n; i += 256) s += partial[i];
#pragma unroll
  for (int off = 1; off < 64; off <<= 1) s += __shfl_xor(s, off, 64);
  __shared__ float wsum[4];
  int wid = threadIdx.x >> 6;
  if ((threadIdx.x & 63) == 0) wsum[wid] = s;
  __syncthreads();
  if (threadIdx.x == 0) out[0] = -(wsum[0] + wsum[1] + wsum[2] + wsum[3]);
}

extern "C" void kernel_launch(void* const* d_in, const int* in_sizes, int n_in,
                              void* d_out, int out_size, void* d_ws, size_t ws_size,
                              hipStream_t stream) {
  const float* x    = (const float*)d_in[0];
  const float* wq   = (const float*)d_in[1];
  const float* wk   = (const float*)d_in[2];
  const float* beta = (const float*)d_in[3];

  char* ws = (char*)d_ws;
  const size_t xb_bytes = (size_t)B_ * S_ * E_ * 2;        // 12,582,912
  const size_t wb_bytes = (size_t)2 * H_ * D_ * E_ * 2;    //  2,359,296
  const size_t qk_bytes = (size_t)B_ * H_ * S_ * D_ * 2;   // 12,582,912
  const size_t rs_bytes = (size_t)4 * NROWS * 4;           //   1,572,864
  unsigned short* xb = (unsigned short*)ws;
  unsigned short* wb = (unsigned short*)(ws + xb_bytes);
  unsigned short* Qb = (unsigned short*)(ws + xb_bytes + wb_bytes);
  unsigned short* Kb = (unsigned short*)(ws + xb_bytes + wb_bytes + qk_bytes);
  float* rowsum      = (float*)(ws + xb_bytes + wb_bytes + 2 * qk_bytes);
  float* partial     = (float*)(ws + xb_bytes + wb_bytes + 2 * qk_bytes + rs_bytes);

  int nx4 = (B_ * S_ * E_) / 4;
  cvt_x_kernel<<<(nx4 + 255) / 256, 256, 0, stream>>>((const float4*)x, (ushort4*)xb, nx4);

  int nw4 = (H_ * D_ * E_) / 4;
  cvt_w_kernel<<<(2 * nw4 + 255) / 256, 256, 0, stream>>>((const float4*)wq, (const float4*)wk,
                                                          beta, (ushort4*)wb, nw4);

  dim3 pgrid((B_ * S_) / 128, (2 * H_ * D_) / 128);   // 64 x 12
  proj_kernel<<<pgrid, 256, 0, stream>>>(xb, wb, Qb, Kb);

  dim3 lgrid(S_ / 256, H_, B_ * 4);                    // 8 x 12 x 16 = 1536 blocks
  lse_kernel<<<lgrid, 256, 0, stream>>>(Qb, Kb, rowsum);

  finish1_kernel<<<NROWS / 256, 256, 0, stream>>>(rowsum, beta, partial);
  finish2_kernel<<<1, 256, 0, stream>>>(partial, NROWS / 256, (float*)d_out);
}

// Round 3
// 84.969 us; speedup vs baseline: 1.1605x; 1.1605x over previous
//
#include <hip/hip_runtime.h>
#include <hip/hip_bf16.h>

typedef __attribute__((ext_vector_type(8))) short short8v;
typedef __attribute__((ext_vector_type(4))) float f32x4;

static constexpr int B_ = 4, S_ = 2048, E_ = 768, H_ = 12, D_ = 64;
static constexpr int NROWS = B_ * H_ * S_;       // 98304
static constexpr float LOG2E = 1.44269504088896340736f;
static constexpr float LN2 = 0.69314718055994530942f;

typedef __attribute__((address_space(3))) unsigned int lds_u32;
typedef const __attribute__((address_space(1))) unsigned int glb_u32;

__device__ __forceinline__ void gload16(const void* g, void* l) {
  __builtin_amdgcn_global_load_lds((glb_u32*)g, (lds_u32*)l, 16, 0, 0);
}

#define VM0 asm volatile("s_waitcnt vmcnt(0)" ::: "memory")
#define VM2 asm volatile("s_waitcnt vmcnt(2)" ::: "memory")
#define VM4 asm volatile("s_waitcnt vmcnt(4)" ::: "memory")
#define BAR __builtin_amdgcn_s_barrier()

__device__ __forceinline__ unsigned short f2bf(float f) {
  union { float f; unsigned int u; } v; v.f = f;
  unsigned int u = v.u;
  unsigned int r = (u + 0x7fffu + ((u >> 16) & 1u)) >> 16;
  return (unsigned short)r;
}

__global__ __launch_bounds__(256) void cvt_x_kernel(const float4* __restrict__ x,
                                                    ushort4* __restrict__ xb, int n4) {
  int i = blockIdx.x * 256 + threadIdx.x;
  if (i >= n4) return;
  float4 v = x[i];
  ushort4 o;
  o.x = f2bf(v.x); o.y = f2bf(v.y); o.z = f2bf(v.z); o.w = f2bf(v.w);
  xb[i] = o;
}

// wb[1536][768]: rows 0..767 = beta[h]*log2e*W^Q; rows 768..1535 = W^K
__global__ __launch_bounds__(256) void cvt_w_kernel(const float4* __restrict__ wq,
                                                    const float4* __restrict__ wk,
                                                    const float* __restrict__ beta,
                                                    ushort4* __restrict__ wb, int n4) {
  int i = blockIdx.x * 256 + threadIdx.x;
  if (i < n4) {
    int row = i / (E_ / 4);
    float sc = beta[row >> 6] * LOG2E;
    float4 v = wq[i];
    ushort4 o;
    o.x = f2bf(v.x * sc); o.y = f2bf(v.y * sc); o.z = f2bf(v.z * sc); o.w = f2bf(v.w * sc);
    wb[i] = o;
  } else if (i < 2 * n4) {
    int j = i - n4;
    float4 v = wk[j];
    ushort4 o;
    o.x = f2bf(v.x); o.y = f2bf(v.y); o.z = f2bf(v.z); o.w = f2bf(v.w);
    wb[i] = o;
  }
}

// GEMM: C[8192,1536] = X[8192,768] * W[1536,768]^T, 128x128 tile, BK=32.
__global__ __launch_bounds__(256) void proj_kernel(const unsigned short* __restrict__ xb,
                                                   const unsigned short* __restrict__ wb,
                                                   unsigned short* __restrict__ Qb,
                                                   unsigned short* __restrict__ Kb) {
  __shared__ unsigned short lA[128 * 32];
  __shared__ unsigned short lB[128 * 32];
  const int mt = blockIdx.x, nt = blockIdx.y;
  const int t = threadIdx.x;
  const int wid = t >> 6, lane = t & 63, l15 = lane & 15, lhi = lane >> 4;
  const int wr = (wid >> 1) * 64, wc = (wid & 1) * 64;

  f32x4 acc[4][4] = {};

  const int row = t >> 2, ch = t & 3;
  const unsigned short* gA = xb + (size_t)(mt * 128 + row) * E_ + ch * 8;
  const unsigned short* gB = wb + (size_t)(nt * 128 + row) * E_ + ch * 8;

  for (int k0 = 0; k0 < E_; k0 += 32) {
    gload16(gA + k0, &lA[t * 8]);
    gload16(gA + (size_t)64 * E_ + k0, &lA[2048 + t * 8]);
    gload16(gB + k0, &lB[t * 8]);
    gload16(gB + (size_t)64 * E_ + k0, &lB[2048 + t * 8]);
    __syncthreads();
    short8v aF[4], bF[4];
#pragma unroll
    for (int m = 0; m < 4; ++m)
      aF[m] = *(const short8v*)&lA[(wr + m * 16 + l15) * 32 + lhi * 8];
#pragma unroll
    for (int n = 0; n < 4; ++n)
      bF[n] = *(const short8v*)&lB[(wc + n * 16 + l15) * 32 + lhi * 8];
#pragma unroll
    for (int m = 0; m < 4; ++m)
#pragma unroll
      for (int n = 0; n < 4; ++n)
        acc[m][n] = __builtin_amdgcn_mfma_f32_16x16x32_bf16(aF[m], bF[n], acc[m][n], 0, 0, 0);
    __syncthreads();
  }

  const int nbase = nt * 128 + wc;
  unsigned short* dst = (nbase < 768) ? Qb : Kb;
  const int nb = (nbase < 768) ? nbase : nbase - 768;
#pragma unroll
  for (int m = 0; m < 4; ++m)
#pragma unroll
    for (int n = 0; n < 4; ++n)
#pragma unroll
      for (int r = 0; r < 4; ++r) {
        int M = mt * 128 + wr + m * 16 + lhi * 4 + r;
        int col = nb + n * 16 + l15;
        int h = col >> 6, d = col & 63;
        int b = M >> 11, s = M & (S_ - 1);
        dst[((((size_t)b * H_ + h) * S_ + s) << 6) + d] = f2bf(acc[m][n][r]);
      }
}

// Stage one 64-row K tile (8 KB) into LDS (256 threads), XOR-swizzled via
// pre-swizzled global source (rule #21: linear LDS dest).
// LDS[row][slot] (16B chunks, slot=0..7) = K[row][slot ^ (row&7)].
__device__ __forceinline__ void stageK(const unsigned short* __restrict__ Kbase, int t0,
                                       int tid, unsigned short* lbuf) {
  const int w = tid >> 6;
  const int r = tid >> 3;                       // 0..31
  const int c = (tid & 7) ^ (r & 7);            // inverse-swizzled source chunk
  const char* src = (const char*)Kbase + ((size_t)(t0 + r) << 7) + (c << 4);
  char* ldst = (char*)lbuf + (w << 10);         // wave-uniform; HW adds lane*16
  gload16(src, ldst);
  gload16(src + (32 << 7), ldst + 4096);        // rows 32..63, same swizzle
}

// 64 q-rows per wave: K-fragments read once from LDS feed 4 row-blocks.
// Diagonal self-exclusion folded in (verified bit-exact in r1/r2): zero the
// diag element of fragment (rb==f) instead of a separate correction pass.
__device__ __forceinline__ void computeTile64(const unsigned short* lbuf, const short8v q[4][2],
                                              f32x4 sp[4], bool isD, int l15, int lhi) {
  short8v kf[4][2];
  const int sw = l15 & 7;
#pragma unroll
  for (int f = 0; f < 4; ++f) {
    const char* p = (const char*)lbuf + ((f * 16 + l15) << 7);
    kf[f][0] = *(const short8v*)(p + ((lhi ^ sw) << 4));
    kf[f][1] = *(const short8v*)(p + (((lhi + 4) ^ sw) << 4));
  }
#pragma unroll
  for (int rb = 0; rb < 4; ++rb) {
    f32x4 acc[4] = {};
    __builtin_amdgcn_s_setprio(1);
#pragma unroll
    for (int f = 0; f < 4; ++f) {
      acc[f] = __builtin_amdgcn_mfma_f32_16x16x32_bf16(q[rb][0], kf[f][0], acc[f], 0, 0, 0);
      acc[f] = __builtin_amdgcn_mfma_f32_16x16x32_bf16(q[rb][1], kf[f][1], acc[f], 0, 0, 0);
    }
    __builtin_amdgcn_s_setprio(0);
#pragma unroll
    for (int f = 0; f < 4; ++f) {
      f32x4 e;
#pragma unroll
      for (int r = 0; r < 4; ++r) e[r] = __builtin_amdgcn_exp2f(acc[f][r]);
      if (isD && f == rb) {
#pragma unroll
        for (int r = 0; r < 4; ++r)
          if (l15 == lhi * 4 + r) e[r] = 0.f;
      }
      sp[rb] += e;                        // v_pk_add_f32 x2
    }
  }
}

// LSE row sums. 4 waves x 64 rows = 256 rows/block; t-range split in 4
// (8 tiles/block). LDS staging shares each K tile across the block's 4 waves
// (4x less global traffic than per-wave loads -- r1/r2 showed private loads
// hit a per-CU MLP cap at ~62us). 4-buffer rotation with 2-tile lookahead
// (vmcnt(4) steady state) so staging latency is covered by ~2 compute tiles
// and the pre-barrier drain wait vanishes. XCD map: all 32 blocks of one
// (b,h) on one XCD -> K panels L2-resident (FETCH_SIZE stays ~12 MB).
__global__ __launch_bounds__(256) void lse_kernel(const unsigned short* __restrict__ Qb,
                                                  const unsigned short* __restrict__ Kb,
                                                  float* __restrict__ rowsum) {
  __shared__ __align__(16) unsigned short lK[4][4096];   // 4 x 8 KB
  const int L = blockIdx.x + 8 * (blockIdx.y + 12 * blockIdx.z);  // 0..1535
  const int xcd = L & 7, j = L >> 3;      // hw round-robins wgid%8 -> XCD
  const int split = j & 3;
  const int st = (j >> 2) & 7;
  const int g = xcd + 8 * (j >> 5);       // (b,h) group, 0..47
  const int h = g % H_, b = g / H_;

  const int tid = threadIdx.x;
  const int wid = tid >> 6, lane = tid & 63;
  const int l15 = lane & 15, lhi = lane >> 4;
  const size_t hb = ((size_t)b * H_ + h) * S_;
  const unsigned short* Qbase = Qb + hb * D_;
  const unsigned short* Kbase = Kb + hb * D_;
  const int s0 = st * 256 + wid * 64;     // 64 rows per wave
  const int tb = split * 512;             // 8 tiles of 64

  short8v q[4][2];
#pragma unroll
  for (int rb = 0; rb < 4; ++rb) {
    const unsigned short* qr = Qbase + (size_t)(s0 + rb * 16 + l15) * D_ + lhi * 8;
    q[rb][0] = *(const short8v*)qr;
    q[rb][1] = *(const short8v*)(qr + 32);
  }

  // tile index (within this split's 8 tiles) holding this wave's diagonal
  const int dtile = ((s0 >> 9) == split) ? ((s0 - tb) >> 6) : -1;

  f32x4 sp[4] = {};                       // sp[rb][r] row partial sums
  stageK(Kbase, tb, tid, lK[0]);
  stageK(Kbase, tb + 64, tid, lK[1]);
  stageK(Kbase, tb + 128, tid, lK[2]);
  int bi = 0;
#pragma unroll 1
  for (int i = 0; i < 6; ++i) {
    VM4;                                   // own stage(i) landed; i+1,i+2 in flight
    BAR;                                   // all waves past compute(i-1) -> buf reuse safe
    if (i < 5) {
      int bs_ = bi + 3; if (bs_ >= 4) bs_ -= 4;
      stageK(Kbase, tb + (i + 3) * 64, tid, lK[bs_]);
    }
    computeTile64(lK[bi], q, sp, i == dtile, l15, lhi);
    if (++bi == 4) bi = 0;
  }
  VM2; BAR;
  computeTile64(lK[bi], q, sp, 6 == dtile, l15, lhi);
  if (++bi == 4) bi = 0;
  VM0; BAR;
  computeTile64(lK[bi], q, sp, 7 == dtile, l15, lhi);

#pragma unroll
  for (int rb = 0; rb < 4; ++rb)
#pragma unroll
    for (int r = 0; r < 4; ++r) {
      float s = sp[rb][r];
#pragma unroll
      for (int off = 1; off < 16; off <<= 1) s += __shfl_xor(s, off, 64);
      if (l15 == 0)
        rowsum[(size_t)split * NROWS + hb + s0 + rb * 16 + lhi * 4 + r] = s;
    }
}

__global__ __launch_bounds__(256) void finish1_kernel(const float* __restrict__ rowsum,
                                                      const float* __restrict__ beta,
                                                      float* __restrict__ partial) {
  int row = blockIdx.x * 256 + threadIdx.x;
  float s = (rowsum[row] + rowsum[NROWS + row]) +
            (rowsum[2 * NROWS + row] + rowsum[3 * NROWS + row]);
  int h = (row >> 11) % H_;
  float c = __builtin_amdgcn_logf(s) * LN2 / beta[h];   // v_log_f32 = log2
#pragma unroll
  for (int off = 1; off < 64; off <<= 1) c += __shfl_xor(c, off, 64);
  __shared__ float wsum[4];
  int wid = threadIdx.x >> 6;
  if ((threadIdx.x & 63) == 0) wsum[wid] = c;
  __syncthreads();
  if (threadIdx.x == 0) partial[blockIdx.x] = wsum[0] + wsum[1] + wsum[2] + wsum[3];
}

__global__ __launch_bounds__(256) void finish2_kernel(const float* __restrict__ partial, int n,
                                                      float* __restrict__ out) {
  float s = 0.f;
  for (int i = threadIdx.x; i < n; i += 256) s += partial[i];
#pragma unroll
  for (int off = 1; off < 64; off <<= 1) s += __shfl_xor(s, off, 64);
  __shared__ float wsum[4];
  int wid = threadIdx.x >> 6;
  if ((threadIdx.x & 63) == 0) wsum[wid] = s;
  __syncthreads();
  if (threadIdx.x == 0) out[0] = -(wsum[0] + wsum[1] + wsum[2] + wsum[3]);
}

extern "C" void kernel_launch(void* const* d_in, const int* in_sizes, int n_in,
                              void* d_out, int out_size, void* d_ws, size_t ws_size,
                              hipStream_t stream) {
  const float* x    = (const float*)d_in[0];
  const float* wq   = (const float*)d_in[1];
  const float* wk   = (const float*)d_in[2];
  const float* beta = (const float*)d_in[3];

  char* ws = (char*)d_ws;
  const size_t xb_bytes = (size_t)B_ * S_ * E_ * 2;        // 12,582,912
  const size_t wb_bytes = (size_t)2 * H_ * D_ * E_ * 2;    //  2,359,296
  const size_t qk_bytes = (size_t)B_ * H_ * S_ * D_ * 2;   // 12,582,912
  const size_t rs_bytes = (size_t)4 * NROWS * 4;           //   1,572,864
  unsigned short* xb = (unsigned short*)ws;
  unsigned short* wb = (unsigned short*)(ws + xb_bytes);
  unsigned short* Qb = (unsigned short*)(ws + xb_bytes + wb_bytes);
  unsigned short* Kb = (unsigned short*)(ws + xb_bytes + wb_bytes + qk_bytes);
  float* rowsum      = (float*)(ws + xb_bytes + wb_bytes + 2 * qk_bytes);
  float* partial     = (float*)(ws + xb_bytes + wb_bytes + 2 * qk_bytes + rs_bytes);

  int nx4 = (B_ * S_ * E_) / 4;
  cvt_x_kernel<<<(nx4 + 255) / 256, 256, 0, stream>>>((const float4*)x, (ushort4*)xb, nx4);

  int nw4 = (H_ * D_ * E_) / 4;
  cvt_w_kernel<<<(2 * nw4 + 255) / 256, 256, 0, stream>>>((const float4*)wq, (const float4*)wk,
                                                          beta, (ushort4*)wb, nw4);

  dim3 pgrid((B_ * S_) / 128, (2 * H_ * D_) / 128);   // 64 x 12
  proj_kernel<<<pgrid, 256, 0, stream>>>(xb, wb, Qb, Kb);

  dim3 lgrid(S_ / 256, H_, B_ * 4);                    // 8 x 12 x 16 = 1536 blocks
  lse_kernel<<<lgrid, 256, 0, stream>>>(Qb, Kb, rowsum);

  finish1_kernel<<<NROWS / 256, 256, 0, stream>>>(rowsum, beta, partial);
  finish2_kernel<<<1, 256, 0, stream>>>(partial, NROWS / 256, (float*)d_out);
}

// Round 4
// 79.663 us; speedup vs baseline: 1.2378x; 1.0666x over previous
//
#include <hip/hip_runtime.h>
#include <hip/hip_bf16.h>

typedef __attribute__((ext_vector_type(8))) short short8v;
typedef __attribute__((ext_vector_type(4))) float f32x4;

static constexpr int B_ = 4, S_ = 2048, E_ = 768, H_ = 12, D_ = 64;
static constexpr int NROWS = B_ * H_ * S_;       // 98304
static constexpr float LOG2E = 1.44269504088896340736f;
static constexpr float LN2 = 0.69314718055994530942f;

typedef __attribute__((address_space(3))) unsigned int lds_u32;
typedef const __attribute__((address_space(1))) unsigned int glb_u32;

__device__ __forceinline__ void gload16(const void* g, void* l) {
  __builtin_amdgcn_global_load_lds((glb_u32*)g, (lds_u32*)l, 16, 0, 0);
}

#define VM0 asm volatile("s_waitcnt vmcnt(0)" ::: "memory")
#define VM2 asm volatile("s_waitcnt vmcnt(2)" ::: "memory")
#define BAR __builtin_amdgcn_s_barrier()

__device__ __forceinline__ unsigned short f2bf(float f) {
  union { float f; unsigned int u; } v; v.f = f;
  unsigned int u = v.u;
  unsigned int r = (u + 0x7fffu + ((u >> 16) & 1u)) >> 16;
  return (unsigned short)r;
}

__global__ __launch_bounds__(256) void cvt_x_kernel(const float4* __restrict__ x,
                                                    ushort4* __restrict__ xb, int n4) {
  int i = blockIdx.x * 256 + threadIdx.x;
  if (i >= n4) return;
  float4 v = x[i];
  ushort4 o;
  o.x = f2bf(v.x); o.y = f2bf(v.y); o.z = f2bf(v.z); o.w = f2bf(v.w);
  xb[i] = o;
}

// wb[1536][768]: rows 0..767 = beta[h]*log2e*W^Q; rows 768..1535 = W^K
__global__ __launch_bounds__(256) void cvt_w_kernel(const float4* __restrict__ wq,
                                                    const float4* __restrict__ wk,
                                                    const float* __restrict__ beta,
                                                    ushort4* __restrict__ wb, int n4) {
  int i = blockIdx.x * 256 + threadIdx.x;
  if (i < n4) {
    int row = i / (E_ / 4);
    float sc = beta[row >> 6] * LOG2E;
    float4 v = wq[i];
    ushort4 o;
    o.x = f2bf(v.x * sc); o.y = f2bf(v.y * sc); o.z = f2bf(v.z * sc); o.w = f2bf(v.w * sc);
    wb[i] = o;
  } else if (i < 2 * n4) {
    int j = i - n4;
    float4 v = wk[j];
    ushort4 o;
    o.x = f2bf(v.x); o.y = f2bf(v.y); o.z = f2bf(v.z); o.w = f2bf(v.w);
    wb[i] = o;
  }
}

// GEMM: C[8192,1536] = X[8192,768] * W[1536,768]^T, 128x128 tile, BK=32.
__global__ __launch_bounds__(256) void proj_kernel(const unsigned short* __restrict__ xb,
                                                   const unsigned short* __restrict__ wb,
                                                   unsigned short* __restrict__ Qb,
                                                   unsigned short* __restrict__ Kb) {
  __shared__ unsigned short lA[128 * 32];
  __shared__ unsigned short lB[128 * 32];
  const int mt = blockIdx.x, nt = blockIdx.y;
  const int t = threadIdx.x;
  const int wid = t >> 6, lane = t & 63, l15 = lane & 15, lhi = lane >> 4;
  const int wr = (wid >> 1) * 64, wc = (wid & 1) * 64;

  f32x4 acc[4][4] = {};

  const int row = t >> 2, ch = t & 3;
  const unsigned short* gA = xb + (size_t)(mt * 128 + row) * E_ + ch * 8;
  const unsigned short* gB = wb + (size_t)(nt * 128 + row) * E_ + ch * 8;

  for (int k0 = 0; k0 < E_; k0 += 32) {
    gload16(gA + k0, &lA[t * 8]);
    gload16(gA + (size_t)64 * E_ + k0, &lA[2048 + t * 8]);
    gload16(gB + k0, &lB[t * 8]);
    gload16(gB + (size_t)64 * E_ + k0, &lB[2048 + t * 8]);
    __syncthreads();
    short8v aF[4], bF[4];
#pragma unroll
    for (int m = 0; m < 4; ++m)
      aF[m] = *(const short8v*)&lA[(wr + m * 16 + l15) * 32 + lhi * 8];
#pragma unroll
    for (int n = 0; n < 4; ++n)
      bF[n] = *(const short8v*)&lB[(wc + n * 16 + l15) * 32 + lhi * 8];
#pragma unroll
    for (int m = 0; m < 4; ++m)
#pragma unroll
      for (int n = 0; n < 4; ++n)
        acc[m][n] = __builtin_amdgcn_mfma_f32_16x16x32_bf16(aF[m], bF[n], acc[m][n], 0, 0, 0);
    __syncthreads();
  }

  const int nbase = nt * 128 + wc;
  unsigned short* dst = (nbase < 768) ? Qb : Kb;
  const int nb = (nbase < 768) ? nbase : nbase - 768;
#pragma unroll
  for (int m = 0; m < 4; ++m)
#pragma unroll
    for (int n = 0; n < 4; ++n)
#pragma unroll
      for (int r = 0; r < 4; ++r) {
        int M = mt * 128 + wr + m * 16 + lhi * 4 + r;
        int col = nb + n * 16 + l15;
        int h = col >> 6, d = col & 63;
        int b = M >> 11, s = M & (S_ - 1);
        dst[((((size_t)b * H_ + h) * S_ + s) << 6) + d] = f2bf(acc[m][n][r]);
      }
}

// Stage one 64-row K tile (8 KB) into LDS (256 threads), XOR-swizzled via
// pre-swizzled global source (rule #21: linear LDS dest).
// LDS[row][slot] (16B chunks, slot=0..7) = K[row][slot ^ (row&7)].
__device__ __forceinline__ void stageK(const unsigned short* __restrict__ Kbase, int t0,
                                       int tid, unsigned short* lbuf) {
  const int w = tid >> 6;
  const int r = tid >> 3;                       // 0..31
  const int c = (tid & 7) ^ (r & 7);            // inverse-swizzled source chunk
  const char* src = (const char*)Kbase + ((size_t)(t0 + r) << 7) + (c << 4);
  char* ldst = (char*)lbuf + (w << 10);         // wave-uniform; HW adds lane*16
  gload16(src, ldst);
  gload16(src + (32 << 7), ldst + 4096);        // rows 32..63, same swizzle
}

// 64 q-rows per wave: K-fragments read once from LDS feed 4 row-blocks.
// Diagonal self-exclusion folded in (bit-exact in r1/r2/r3): zero the diag
// element of fragment (rb==f) instead of a separate correction pass.
// No setprio (r3 suspect for VGPR inflation 64->104 -> occupancy loss).
__device__ __forceinline__ void computeTile64(const unsigned short* lbuf, const short8v q[4][2],
                                              f32x4 sp[4], bool isD, int l15, int lhi) {
  short8v kf[4][2];
  const int sw = l15 & 7;
#pragma unroll
  for (int f = 0; f < 4; ++f) {
    const char* p = (const char*)lbuf + ((f * 16 + l15) << 7);
    kf[f][0] = *(const short8v*)(p + ((lhi ^ sw) << 4));
    kf[f][1] = *(const short8v*)(p + (((lhi + 4) ^ sw) << 4));
  }
#pragma unroll
  for (int rb = 0; rb < 4; ++rb) {
    f32x4 acc[4] = {};
#pragma unroll
    for (int f = 0; f < 4; ++f) {
      acc[f] = __builtin_amdgcn_mfma_f32_16x16x32_bf16(q[rb][0], kf[f][0], acc[f], 0, 0, 0);
      acc[f] = __builtin_amdgcn_mfma_f32_16x16x32_bf16(q[rb][1], kf[f][1], acc[f], 0, 0, 0);
    }
#pragma unroll
    for (int f = 0; f < 4; ++f) {
      f32x4 e;
#pragma unroll
      for (int r = 0; r < 4; ++r) e[r] = __builtin_amdgcn_exp2f(acc[f][r]);
      if (isD && f == rb) {
#pragma unroll
        for (int r = 0; r < 4; ++r)
          if (l15 == lhi * 4 + r) e[r] = 0.f;
      }
      sp[rb] += e;                        // v_pk_add_f32 x2
    }
  }
}

// LSE row sums. 4 waves x 64 rows = 256 rows/block; t-range split in 4
// (8 tiles/block). 3-buffer rotation, one barrier per tile (the proven 45us
// r0 operating point: VGPR 64, 24KB LDS, 6 blocks/CU -- r3 showed occupancy
// is the binding constraint; deeper pipelines that cost VGPR/LDS regress).
// Diagonal exclusion folded into the main loop (removes the 9th correction
// tile on 25% of blocks + its private global loadK path).
__global__ __launch_bounds__(256) void lse_kernel(const unsigned short* __restrict__ Qb,
                                                  const unsigned short* __restrict__ Kb,
                                                  float* __restrict__ rowsum) {
  __shared__ __align__(16) unsigned short lK[3][4096];   // 3 x 8 KB
  const int L = blockIdx.x + 8 * (blockIdx.y + 12 * blockIdx.z);  // 0..1535
  const int xcd = L & 7, j = L >> 3;      // hw round-robins wgid%8 -> XCD
  const int split = j & 3;
  const int st = (j >> 2) & 7;
  const int g = xcd + 8 * (j >> 5);       // (b,h) group, 0..47
  const int h = g % H_, b = g / H_;

  const int tid = threadIdx.x;
  const int wid = tid >> 6, lane = tid & 63;
  const int l15 = lane & 15, lhi = lane >> 4;
  const size_t hb = ((size_t)b * H_ + h) * S_;
  const unsigned short* Qbase = Qb + hb * D_;
  const unsigned short* Kbase = Kb + hb * D_;
  const int s0 = st * 256 + wid * 64;     // 64 rows per wave
  const int tb = split * 512;             // 8 tiles of 64

  short8v q[4][2];
#pragma unroll
  for (int rb = 0; rb < 4; ++rb) {
    const unsigned short* qr = Qbase + (size_t)(s0 + rb * 16 + l15) * D_ + lhi * 8;
    q[rb][0] = *(const short8v*)qr;
    q[rb][1] = *(const short8v*)(qr + 32);
  }

  // tile index (within this split's 8 tiles) holding this wave's diagonal
  const int dtile = ((s0 >> 9) == split) ? ((s0 - tb) >> 6) : -1;

  f32x4 sp[4] = {};                       // sp[rb][r] row partial sums
  stageK(Kbase, tb, tid, lK[0]);
  stageK(Kbase, tb + 64, tid, lK[1]);
  int bi = 0;
#pragma unroll 1
  for (int i = 0; i < 7; ++i) {
    VM2;                                   // own tile-i loads done (only i+1 in flight)
    BAR;                                   // tile-i fully visible; compute(i-1) done
    if (i < 6) {
      int bs_ = bi + 2; if (bs_ >= 3) bs_ -= 3;
      stageK(Kbase, tb + (i + 2) * 64, tid, lK[bs_]);
    }
    computeTile64(lK[bi], q, sp, i == dtile, l15, lhi);
    if (++bi == 3) bi = 0;
  }
  VM0; BAR;
  computeTile64(lK[bi], q, sp, 7 == dtile, l15, lhi);

#pragma unroll
  for (int rb = 0; rb < 4; ++rb)
#pragma unroll
    for (int r = 0; r < 4; ++r) {
      float s = sp[rb][r];
#pragma unroll
      for (int off = 1; off < 16; off <<= 1) s += __shfl_xor(s, off, 64);
      if (l15 == 0)
        rowsum[(size_t)split * NROWS + hb + s0 + rb * 16 + lhi * 4 + r] = s;
    }
}

__global__ __launch_bounds__(256) void finish1_kernel(const float* __restrict__ rowsum,
                                                      const float* __restrict__ beta,
                                                      float* __restrict__ partial) {
  int row = blockIdx.x * 256 + threadIdx.x;
  float s = (rowsum[row] + rowsum[NROWS + row]) +
            (rowsum[2 * NROWS + row] + rowsum[3 * NROWS + row]);
  int h = (row >> 11) % H_;
  float c = __builtin_amdgcn_logf(s) * LN2 / beta[h];   // v_log_f32 = log2
#pragma unroll
  for (int off = 1; off < 64; off <<= 1) c += __shfl_xor(c, off, 64);
  __shared__ float wsum[4];
  int wid = threadIdx.x >> 6;
  if ((threadIdx.x & 63) == 0) wsum[wid] = c;
  __syncthreads();
  if (threadIdx.x == 0) partial[blockIdx.x] = wsum[0] + wsum[1] + wsum[2] + wsum[3];
}

__global__ __launch_bounds__(256) void finish2_kernel(const float* __restrict__ partial, int n,
                                                      float* __restrict__ out) {
  float s = 0.f;
  for (int i = threadIdx.x; i < n; i += 256) s += partial[i];
#pragma unroll
  for (int off = 1; off < 64; off <<= 1) s += __shfl_xor(s, off, 64);
  __shared__ float wsum[4];
  int wid = threadIdx.x >> 6;
  if ((threadIdx.x & 63) == 0) wsum[wid] = s;
  __syncthreads();
  if (threadIdx.x == 0) out[0] = -(wsum[0] + wsum[1] + wsum[2] + wsum[3]);
}

extern "C" void kernel_launch(void* const* d_in, const int* in_sizes, int n_in,
                              void* d_out, int out_size, void* d_ws, size_t ws_size,
                              hipStream_t stream) {
  const float* x    = (const float*)d_in[0];
  const float* wq   = (const float*)d_in[1];
  const float* wk   = (const float*)d_in[2];
  const float* beta = (const float*)d_in[3];

  char* ws = (char*)d_ws;
  const size_t xb_bytes = (size_t)B_ * S_ * E_ * 2;        // 12,582,912
  const size_t wb_bytes = (size_t)2 * H_ * D_ * E_ * 2;    //  2,359,296
  const size_t qk_bytes = (size_t)B_ * H_ * S_ * D_ * 2;   // 12,582,912
  const size_t rs_bytes = (size_t)4 * NROWS * 4;           //   1,572,864
  unsigned short* xb = (unsigned short*)ws;
  unsigned short* wb = (unsigned short*)(ws + xb_bytes);
  unsigned short* Qb = (unsigned short*)(ws + xb_bytes + wb_bytes);
  unsigned short* Kb = (unsigned short*)(ws + xb_bytes + wb_bytes + qk_bytes);
  float* rowsum      = (float*)(ws + xb_bytes + wb_bytes + 2 * qk_bytes);
  float* partial     = (float*)(ws + xb_bytes + wb_bytes + 2 * qk_bytes + rs_bytes);

  int nx4 = (B_ * S_ * E_) / 4;
  cvt_x_kernel<<<(nx4 + 255) / 256, 256, 0, stream>>>((const float4*)x, (ushort4*)xb, nx4);

  int nw4 = (H_ * D_ * E_) / 4;
  cvt_w_kernel<<<(2 * nw4 + 255) / 256, 256, 0, stream>>>((const float4*)wq, (const float4*)wk,
                                                          beta, (ushort4*)wb, nw4);

  dim3 pgrid((B_ * S_) / 128, (2 * H_ * D_) / 128);   // 64 x 12
  proj_kernel<<<pgrid, 256, 0, stream>>>(xb, wb, Qb, Kb);

  dim3 lgrid(S_ / 256, H_, B_ * 4);                    // 8 x 12 x 16 = 1536 blocks
  lse_kernel<<<lgrid, 256, 0, stream>>>(Qb, Kb, rowsum);

  finish1_kernel<<<NROWS / 256, 256, 0, stream>>>(rowsum, beta, partial);
  finish2_kernel<<<1, 256, 0, stream>>>(partial, NROWS / 256, (float*)d_out);
}

// Round 5
// 77.922 us; speedup vs baseline: 1.2654x; 1.0223x over previous
//
#include <hip/hip_runtime.h>
#include <hip/hip_bf16.h>

typedef __attribute__((ext_vector_type(8))) short short8v;
typedef __attribute__((ext_vector_type(4))) float f32x4;

static constexpr int B_ = 4, S_ = 2048, E_ = 768, H_ = 12, D_ = 64;
static constexpr int NROWS = B_ * H_ * S_;       // 98304
static constexpr float LOG2E = 1.44269504088896340736f;
static constexpr float LN2 = 0.69314718055994530942f;

typedef __attribute__((address_space(3))) unsigned int lds_u32;
typedef const __attribute__((address_space(1))) unsigned int glb_u32;

__device__ __forceinline__ void gload16(const void* g, void* l) {
  __builtin_amdgcn_global_load_lds((glb_u32*)g, (lds_u32*)l, 16, 0, 0);
}

#define VM0 asm volatile("s_waitcnt vmcnt(0)" ::: "memory")
#define VM2 asm volatile("s_waitcnt vmcnt(2)" ::: "memory")
#define BAR __builtin_amdgcn_s_barrier()

__device__ __forceinline__ unsigned short f2bf(float f) {
  union { float f; unsigned int u; } v; v.f = f;
  unsigned int u = v.u;
  unsigned int r = (u + 0x7fffu + ((u >> 16) & 1u)) >> 16;
  return (unsigned short)r;
}

// wb[1536][768]: rows 0..767 = beta[h]*log2e*W^Q; rows 768..1535 = W^K
__global__ __launch_bounds__(256) void cvt_w_kernel(const float4* __restrict__ wq,
                                                    const float4* __restrict__ wk,
                                                    const float* __restrict__ beta,
                                                    ushort4* __restrict__ wb, int n4) {
  int i = blockIdx.x * 256 + threadIdx.x;
  if (i < n4) {
    int row = i / (E_ / 4);
    float sc = beta[row >> 6] * LOG2E;
    float4 v = wq[i];
    ushort4 o;
    o.x = f2bf(v.x * sc); o.y = f2bf(v.y * sc); o.z = f2bf(v.z * sc); o.w = f2bf(v.w * sc);
    wb[i] = o;
  } else if (i < 2 * n4) {
    int j = i - n4;
    float4 v = wk[j];
    ushort4 o;
    o.x = f2bf(v.x); o.y = f2bf(v.y); o.z = f2bf(v.z); o.w = f2bf(v.w);
    wb[i] = o;
  }
}

// GEMM: C[8192,1536] = X[8192,768] * W[1536,768]^T, 128x128 tile, BK=32.
// x->bf16 conversion FUSED: A-tile staged as raw f32 via global_load_lds
// (saves the cvt_x kernel's 50 MB HBM round-trip), fragments converted
// in-register with v_cvt_pk_bf16_f32 (RTNE, identical rounding to f2bf).
// A-tile chunk-swizzle: LDS[row][slot] (16B chunks, slot=0..7) =
// x[row][slot ^ (row&7)] via pre-swizzled global source (rule #21);
// fragment read hits <=8 lanes per 16B slot = conflict-free for b128.
__global__ __launch_bounds__(256) void proj_kernel(const float* __restrict__ x,
                                                   const unsigned short* __restrict__ wb,
                                                   unsigned short* __restrict__ Qb,
                                                   unsigned short* __restrict__ Kb) {
  __shared__ float lAf[128 * 32];               // 16 KB, f32 A-tile
  __shared__ unsigned short lB[128 * 32];       // 8 KB, bf16 B-tile
  const int mt = blockIdx.x, nt = blockIdx.y;
  const int t = threadIdx.x;
  const int wid = t >> 6, lane = t & 63, l15 = lane & 15, lhi = lane >> 4;
  const int wr = (wid >> 1) * 64, wc = (wid & 1) * 64;

  f32x4 acc[4][4] = {};

  // A staging geometry: chunk c = p*256 + t; row = p*32 + (t>>3); slot = t&7;
  // source chunk = slot ^ (row&7)  (row&7 == (t>>3)&7 since p*32 % 8 == 0)
  const int r3 = t >> 3;                        // 0..31
  const int cs = (t & 7) ^ (r3 & 7);            // inverse-swizzled source chunk
  const float* gA = x + (size_t)(mt * 128 + r3) * E_ + cs * 4;

  const int row = t >> 2, ch = t & 3;
  const unsigned short* gB = wb + (size_t)(nt * 128 + row) * E_ + ch * 8;

  for (int k0 = 0; k0 < E_; k0 += 32) {
    gload16(gA + k0,                (char*)lAf + t * 16);            // rows  0..31
    gload16(gA + 32 * E_ + k0,      (char*)lAf + 4096 + t * 16);     // rows 32..63
    gload16(gA + 64 * E_ + k0,      (char*)lAf + 8192 + t * 16);     // rows 64..95
    gload16(gA + 96 * E_ + k0,      (char*)lAf + 12288 + t * 16);    // rows 96..127
    gload16(gB + k0,                &lB[t * 8]);
    gload16(gB + (size_t)64 * E_ + k0, &lB[2048 + t * 8]);
    __syncthreads();
    short8v aF[4], bF[4];
    const int sw_ = l15 & 7;
#pragma unroll
    for (int m = 0; m < 4; ++m) {
      const int r = wr + m * 16 + l15;
      const float* base = lAf + r * 32;
      f32x4 u0 = *(const f32x4*)(base + ((((lhi << 1)    ) ^ sw_) << 2));
      f32x4 u1 = *(const f32x4*)(base + ((((lhi << 1) | 1) ^ sw_) << 2));
      union { short8v s8; unsigned int u[4]; } af;
      asm("v_cvt_pk_bf16_f32 %0, %1, %2" : "=v"(af.u[0]) : "v"(u0[0]), "v"(u0[1]));
      asm("v_cvt_pk_bf16_f32 %0, %1, %2" : "=v"(af.u[1]) : "v"(u0[2]), "v"(u0[3]));
      asm("v_cvt_pk_bf16_f32 %0, %1, %2" : "=v"(af.u[2]) : "v"(u1[0]), "v"(u1[1]));
      asm("v_cvt_pk_bf16_f32 %0, %1, %2" : "=v"(af.u[3]) : "v"(u1[2]), "v"(u1[3]));
      aF[m] = af.s8;
    }
#pragma unroll
    for (int n = 0; n < 4; ++n)
      bF[n] = *(const short8v*)&lB[(wc + n * 16 + l15) * 32 + lhi * 8];
#pragma unroll
    for (int m = 0; m < 4; ++m)
#pragma unroll
      for (int n = 0; n < 4; ++n)
        acc[m][n] = __builtin_amdgcn_mfma_f32_16x16x32_bf16(aF[m], bF[n], acc[m][n], 0, 0, 0);
    __syncthreads();
  }

  const int nbase = nt * 128 + wc;
  unsigned short* dst = (nbase < 768) ? Qb : Kb;
  const int nb = (nbase < 768) ? nbase : nbase - 768;
#pragma unroll
  for (int m = 0; m < 4; ++m)
#pragma unroll
    for (int n = 0; n < 4; ++n)
#pragma unroll
      for (int r = 0; r < 4; ++r) {
        int M = mt * 128 + wr + m * 16 + lhi * 4 + r;
        int col = nb + n * 16 + l15;
        int h = col >> 6, d = col & 63;
        int b = M >> 11, s = M & (S_ - 1);
        dst[((((size_t)b * H_ + h) * S_ + s) << 6) + d] = f2bf(acc[m][n][r]);
      }
}

// Stage one 64-row K tile (8 KB) into LDS (256 threads), XOR-swizzled via
// pre-swizzled global source (rule #21: linear LDS dest).
// LDS[row][slot] (16B chunks, slot=0..7) = K[row][slot ^ (row&7)].
__device__ __forceinline__ void stageK(const unsigned short* __restrict__ Kbase, int t0,
                                       int tid, unsigned short* lbuf) {
  const int w = tid >> 6;
  const int r = tid >> 3;                       // 0..31
  const int c = (tid & 7) ^ (r & 7);            // inverse-swizzled source chunk
  const char* src = (const char*)Kbase + ((size_t)(t0 + r) << 7) + (c << 4);
  char* ldst = (char*)lbuf + (w << 10);         // wave-uniform; HW adds lane*16
  gload16(src, ldst);
  gload16(src + (32 << 7), ldst + 4096);        // rows 32..63, same swizzle
}

// 64 q-rows per wave: K-fragments read once from LDS feed 4 row-blocks.
// Diagonal self-exclusion folded in (bit-exact r1-r4): zero the diag
// element of fragment (rb==f) instead of a separate correction pass.
__device__ __forceinline__ void computeTile64(const unsigned short* lbuf, const short8v q[4][2],
                                              f32x4 sp[4], bool isD, int l15, int lhi) {
  short8v kf[4][2];
  const int sw = l15 & 7;
#pragma unroll
  for (int f = 0; f < 4; ++f) {
    const char* p = (const char*)lbuf + ((f * 16 + l15) << 7);
    kf[f][0] = *(const short8v*)(p + ((lhi ^ sw) << 4));
    kf[f][1] = *(const short8v*)(p + (((lhi + 4) ^ sw) << 4));
  }
#pragma unroll
  for (int rb = 0; rb < 4; ++rb) {
    f32x4 acc[4] = {};
#pragma unroll
    for (int f = 0; f < 4; ++f) {
      acc[f] = __builtin_amdgcn_mfma_f32_16x16x32_bf16(q[rb][0], kf[f][0], acc[f], 0, 0, 0);
      acc[f] = __builtin_amdgcn_mfma_f32_16x16x32_bf16(q[rb][1], kf[f][1], acc[f], 0, 0, 0);
    }
#pragma unroll
    for (int f = 0; f < 4; ++f) {
      f32x4 e;
#pragma unroll
      for (int r = 0; r < 4; ++r) e[r] = __builtin_amdgcn_exp2f(acc[f][r]);
      if (isD && f == rb) {
#pragma unroll
        for (int r = 0; r < 4; ++r)
          if (l15 == lhi * 4 + r) e[r] = 0.f;
      }
      sp[rb] += e;                        // v_pk_add_f32 x2
    }
  }
}

// LSE row sums. 4 waves x 64 rows = 256 rows/block; t-range split in 4
// (8 tiles/block). 3-buffer rotation, one barrier per tile (proven best
// operating point across r0-r4: deeper pipelines/LDS-free/reg-dbuf all
// regress or tie; lse plateaus at ~45us, exp2-VALU dominated).
__global__ __launch_bounds__(256) void lse_kernel(const unsigned short* __restrict__ Qb,
                                                  const unsigned short* __restrict__ Kb,
                                                  float* __restrict__ rowsum) {
  __shared__ __align__(16) unsigned short lK[3][4096];   // 3 x 8 KB
  const int L = blockIdx.x + 8 * (blockIdx.y + 12 * blockIdx.z);  // 0..1535
  const int xcd = L & 7, j = L >> 3;      // hw round-robins wgid%8 -> XCD
  const int split = j & 3;
  const int st = (j >> 2) & 7;
  const int g = xcd + 8 * (j >> 5);       // (b,h) group, 0..47
  const int h = g % H_, b = g / H_;

  const int tid = threadIdx.x;
  const int wid = tid >> 6, lane = tid & 63;
  const int l15 = lane & 15, lhi = lane >> 4;
  const size_t hb = ((size_t)b * H_ + h) * S_;
  const unsigned short* Qbase = Qb + hb * D_;
  const unsigned short* Kbase = Kb + hb * D_;
  const int s0 = st * 256 + wid * 64;     // 64 rows per wave
  const int tb = split * 512;             // 8 tiles of 64

  short8v q[4][2];
#pragma unroll
  for (int rb = 0; rb < 4; ++rb) {
    const unsigned short* qr = Qbase + (size_t)(s0 + rb * 16 + l15) * D_ + lhi * 8;
    q[rb][0] = *(const short8v*)qr;
    q[rb][1] = *(const short8v*)(qr + 32);
  }

  // tile index (within this split's 8 tiles) holding this wave's diagonal
  const int dtile = ((s0 >> 9) == split) ? ((s0 - tb) >> 6) : -1;

  f32x4 sp[4] = {};                       // sp[rb][r] row partial sums
  stageK(Kbase, tb, tid, lK[0]);
  stageK(Kbase, tb + 64, tid, lK[1]);
  int bi = 0;
#pragma unroll 1
  for (int i = 0; i < 7; ++i) {
    VM2;                                   // own tile-i loads done (only i+1 in flight)
    BAR;                                   // tile-i fully visible; compute(i-1) done
    if (i < 6) {
      int bs_ = bi + 2; if (bs_ >= 3) bs_ -= 3;
      stageK(Kbase, tb + (i + 2) * 64, tid, lK[bs_]);
    }
    computeTile64(lK[bi], q, sp, i == dtile, l15, lhi);
    if (++bi == 3) bi = 0;
  }
  VM0; BAR;
  computeTile64(lK[bi], q, sp, 7 == dtile, l15, lhi);

#pragma unroll
  for (int rb = 0; rb < 4; ++rb)
#pragma unroll
    for (int r = 0; r < 4; ++r) {
      float s = sp[rb][r];
#pragma unroll
      for (int off = 1; off < 16; off <<= 1) s += __shfl_xor(s, off, 64);
      if (l15 == 0)
        rowsum[(size_t)split * NROWS + hb + s0 + rb * 16 + lhi * 4 + r] = s;
    }
}

__global__ __launch_bounds__(256) void finish1_kernel(const float* __restrict__ rowsum,
                                                      const float* __restrict__ beta,
                                                      float* __restrict__ partial) {
  int row = blockIdx.x * 256 + threadIdx.x;
  float s = (rowsum[row] + rowsum[NROWS + row]) +
            (rowsum[2 * NROWS + row] + rowsum[3 * NROWS + row]);
  int h = (row >> 11) % H_;
  float c = __builtin_amdgcn_logf(s) * LN2 / beta[h];   // v_log_f32 = log2
#pragma unroll
  for (int off = 1; off < 64; off <<= 1) c += __shfl_xor(c, off, 64);
  __shared__ float wsum[4];
  int wid = threadIdx.x >> 6;
  if ((threadIdx.x & 63) == 0) wsum[wid] = c;
  __syncthreads();
  if (threadIdx.x == 0) partial[blockIdx.x] = wsum[0] + wsum[1] + wsum[2] + wsum[3];
}

__global__ __launch_bounds__(256) void finish2_kernel(const float* __restrict__ partial, int n,
                                                      float* __restrict__ out) {
  float s = 0.f;
  for (int i = threadIdx.x; i < n; i += 256) s += partial[i];
#pragma unroll
  for (int off = 1; off < 64; off <<= 1) s += __shfl_xor(s, off, 64);
  __shared__ float wsum[4];
  int wid = threadIdx.x >> 6;
  if ((threadIdx.x & 63) == 0) wsum[wid] = s;
  __syncthreads();
  if (threadIdx.x == 0) out[0] = -(wsum[0] + wsum[1] + wsum[2] + wsum[3]);
}

extern "C" void kernel_launch(void* const* d_in, const int* in_sizes, int n_in,
                              void* d_out, int out_size, void* d_ws, size_t ws_size,
                              hipStream_t stream) {
  const float* x    = (const float*)d_in[0];
  const float* wq   = (const float*)d_in[1];
  const float* wk   = (const float*)d_in[2];
  const float* beta = (const float*)d_in[3];

  char* ws = (char*)d_ws;
  const size_t wb_bytes = (size_t)2 * H_ * D_ * E_ * 2;    //  2,359,296
  const size_t qk_bytes = (size_t)B_ * H_ * S_ * D_ * 2;   // 12,582,912
  const size_t rs_bytes = (size_t)4 * NROWS * 4;           //   1,572,864
  unsigned short* wb = (unsigned short*)ws;
  unsigned short* Qb = (unsigned short*)(ws + wb_bytes);
  unsigned short* Kb = (unsigned short*)(ws + wb_bytes + qk_bytes);
  float* rowsum      = (float*)(ws + wb_bytes + 2 * qk_bytes);
  float* partial     = (float*)(ws + wb_bytes + 2 * qk_bytes + rs_bytes);

  int nw4 = (H_ * D_ * E_) / 4;
  cvt_w_kernel<<<(2 * nw4 + 255) / 256, 256, 0, stream>>>((const float4*)wq, (const float4*)wk,
                                                          beta, (ushort4*)wb, nw4);

  dim3 pgrid((B_ * S_) / 128, (2 * H_ * D_) / 128);   // 64 x 12
  proj_kernel<<<pgrid, 256, 0, stream>>>(x, wb, Qb, Kb);

  dim3 lgrid(S_ / 256, H_, B_ * 4);                    // 8 x 12 x 16 = 1536 blocks
  lse_kernel<<<lgrid, 256, 0, stream>>>(Qb, Kb, rowsum);

  finish1_kernel<<<NROWS / 256, 256, 0, stream>>>(rowsum, beta, partial);
  finish2_kernel<<<1, 256, 0, stream>>>(partial, NROWS / 256, (float*)d_out);
}

// Round 6
// 76.282 us; speedup vs baseline: 1.2926x; 1.0215x over previous
//
#include <hip/hip_runtime.h>
#include <hip/hip_bf16.h>

typedef __attribute__((ext_vector_type(8))) short short8v;
typedef __attribute__((ext_vector_type(4))) float f32x4;

static constexpr int B_ = 4, S_ = 2048, E_ = 768, H_ = 12, D_ = 64;
static constexpr int NROWS = B_ * H_ * S_;       // 98304
static constexpr float LOG2E = 1.44269504088896340736f;
static constexpr float LN2 = 0.69314718055994530942f;

typedef __attribute__((address_space(3))) unsigned int lds_u32;
typedef const __attribute__((address_space(1))) unsigned int glb_u32;

__device__ __forceinline__ void gload16(const void* g, void* l) {
  __builtin_amdgcn_global_load_lds((glb_u32*)g, (lds_u32*)l, 16, 0, 0);
}

#define VM0 asm volatile("s_waitcnt vmcnt(0)" ::: "memory")
#define VM2 asm volatile("s_waitcnt vmcnt(2)" ::: "memory")
#define VM4 asm volatile("s_waitcnt vmcnt(4)" ::: "memory")
#define LG0 asm volatile("s_waitcnt lgkmcnt(0)" ::: "memory")
#define BAR __builtin_amdgcn_s_barrier()

__device__ __forceinline__ unsigned short f2bf(float f) {
  union { float f; unsigned int u; } v; v.f = f;
  unsigned int u = v.u;
  unsigned int r = (u + 0x7fffu + ((u >> 16) & 1u)) >> 16;
  return (unsigned short)r;
}

// wb[1536][768]: rows 0..767 = beta[h]*log2e*W^Q; rows 768..1535 = W^K
__global__ __launch_bounds__(256) void cvt_w_kernel(const float4* __restrict__ wq,
                                                    const float4* __restrict__ wk,
                                                    const float* __restrict__ beta,
                                                    ushort4* __restrict__ wb, int n4) {
  int i = blockIdx.x * 256 + threadIdx.x;
  if (i < n4) {
    int row = i / (E_ / 4);
    float sc = beta[row >> 6] * LOG2E;
    float4 v = wq[i];
    ushort4 o;
    o.x = f2bf(v.x * sc); o.y = f2bf(v.y * sc); o.z = f2bf(v.z * sc); o.w = f2bf(v.w * sc);
    wb[i] = o;
  } else if (i < 2 * n4) {
    int j = i - n4;
    float4 v = wk[j];
    ushort4 o;
    o.x = f2bf(v.x); o.y = f2bf(v.y); o.z = f2bf(v.z); o.w = f2bf(v.w);
    wb[i] = o;
  }
}

// GEMM: C[8192,1536] = X[8192,768] * W[1536,768]^T, 128x128 tile, BK=32.
// x->bf16 fused in the STAGING path (r5 lesson: fragment-path cvt doubled
// A LDS traffic + put 16 cvt/k-step in the MFMA-feeding path; this version
// stages A via regs: 4x global f32x4 -> 8x v_cvt_pk_bf16_f32 -> 2x
// ds_write_b128 bf16). A-loads for k+1 are issued before the compute
// barrier and stay in flight across it (raw s_barrier + counted vmcnt,
// never drained to 0 in the loop -- T4). Chunk-XOR swizzle (c ^= row&3) on
// both A (ds_write side) and B (pre-swizzled global source, same involution
// as lse's stageK) cuts fragment-read bank conflicts.
__global__ __launch_bounds__(256) void proj_kernel(const float* __restrict__ x,
                                                   const unsigned short* __restrict__ wb,
                                                   unsigned short* __restrict__ Qb,
                                                   unsigned short* __restrict__ Kb) {
  __shared__ unsigned short lA[128 * 32];       // 8 KB bf16, LDS[r][c]=X[r][c^(r&3)]
  __shared__ unsigned short lB[128 * 32];       // 8 KB bf16, same swizzle
  const int mt = blockIdx.x, nt = blockIdx.y;
  const int t = threadIdx.x;
  const int wid = t >> 6, lane = t & 63, l15 = lane & 15, lhi = lane >> 4;
  const int wr = (wid >> 1) * 64, wc = (wid & 1) * 64;

  f32x4 acc[4][4] = {};

  const int row = t >> 2, ch = t & 3;           // row 0..63, dest chunk 0..3
  const int chs = ch ^ (row & 3);               // inverse-swizzled source chunk
  const float* gA = x + (size_t)(mt * 128 + row) * E_ + chs * 8;
  const unsigned short* gB = wb + (size_t)(nt * 128 + row) * E_ + chs * 8;

  // prologue: issue A f32 loads for k0=0
  f32x4 a0 = *(const f32x4*)(gA);
  f32x4 a1 = *(const f32x4*)(gA + 4);
  f32x4 a2 = *(const f32x4*)(gA + 64 * E_);
  f32x4 a3 = *(const f32x4*)(gA + 64 * E_ + 4);

  for (int k0 = 0; k0 < E_; k0 += 32) {
    BAR;                                        // prev compute done: lA/lB reusable
    gload16(gB + k0, &lB[t * 8]);
    gload16(gB + (size_t)64 * E_ + k0, &lB[2048 + t * 8]);
    // outstanding: aregs(k0) x4 (oldest), B(k0) x2 -> vmcnt(2): aregs landed
    VM2;
    union { short8v s8; unsigned int u[4]; } c0, c1;
    asm("v_cvt_pk_bf16_f32 %0, %1, %2" : "=v"(c0.u[0]) : "v"(a0[0]), "v"(a0[1]));
    asm("v_cvt_pk_bf16_f32 %0, %1, %2" : "=v"(c0.u[1]) : "v"(a0[2]), "v"(a0[3]));
    asm("v_cvt_pk_bf16_f32 %0, %1, %2" : "=v"(c0.u[2]) : "v"(a1[0]), "v"(a1[1]));
    asm("v_cvt_pk_bf16_f32 %0, %1, %2" : "=v"(c0.u[3]) : "v"(a1[2]), "v"(a1[3]));
    asm("v_cvt_pk_bf16_f32 %0, %1, %2" : "=v"(c1.u[0]) : "v"(a2[0]), "v"(a2[1]));
    asm("v_cvt_pk_bf16_f32 %0, %1, %2" : "=v"(c1.u[1]) : "v"(a2[2]), "v"(a2[3]));
    asm("v_cvt_pk_bf16_f32 %0, %1, %2" : "=v"(c1.u[2]) : "v"(a3[0]), "v"(a3[1]));
    asm("v_cvt_pk_bf16_f32 %0, %1, %2" : "=v"(c1.u[3]) : "v"(a3[2]), "v"(a3[3]));
    *(short8v*)&lA[row * 32 + ch * 8] = c0.s8;          // rows 0..63
    *(short8v*)&lA[(row + 64) * 32 + ch * 8] = c1.s8;   // rows 64..127
    if (k0 + 32 < E_) {
      a0 = *(const f32x4*)(gA + k0 + 32);
      a1 = *(const f32x4*)(gA + k0 + 36);
      a2 = *(const f32x4*)(gA + 64 * E_ + k0 + 32);
      a3 = *(const f32x4*)(gA + 64 * E_ + k0 + 36);
      LG0;                                      // ds_writes visible
      VM4;                                      // B(k0) landed; aregs(k0+32) in flight
    } else {
      LG0;
      VM0;                                      // final tile: drain everything
    }
    BAR;                                        // lA/lB fully staged for all waves
    short8v aF[4], bF[4];
#pragma unroll
    for (int m = 0; m < 4; ++m) {
      const int r = wr + m * 16 + l15;
      aF[m] = *(const short8v*)&lA[r * 32 + ((lhi ^ (l15 & 3)) << 3)];
    }
#pragma unroll
    for (int n = 0; n < 4; ++n) {
      const int r = wc + n * 16 + l15;
      bF[n] = *(const short8v*)&lB[r * 32 + ((lhi ^ (l15 & 3)) << 3)];
    }
#pragma unroll
    for (int m = 0; m < 4; ++m)
#pragma unroll
      for (int n = 0; n < 4; ++n)
        acc[m][n] = __builtin_amdgcn_mfma_f32_16x16x32_bf16(aF[m], bF[n], acc[m][n], 0, 0, 0);
  }

  const int nbase = nt * 128 + wc;
  unsigned short* dst = (nbase < 768) ? Qb : Kb;
  const int nb = (nbase < 768) ? nbase : nbase - 768;
#pragma unroll
  for (int m = 0; m < 4; ++m)
#pragma unroll
    for (int n = 0; n < 4; ++n)
#pragma unroll
      for (int r = 0; r < 4; ++r) {
        int M = mt * 128 + wr + m * 16 + lhi * 4 + r;
        int col = nb + n * 16 + l15;
        int h = col >> 6, d = col & 63;
        int b = M >> 11, s = M & (S_ - 1);
        dst[((((size_t)b * H_ + h) * S_ + s) << 6) + d] = f2bf(acc[m][n][r]);
      }
}

// Stage one 64-row K tile (8 KB) into LDS (256 threads), XOR-swizzled via
// pre-swizzled global source (rule #21: linear LDS dest).
// LDS[row][slot] (16B chunks, slot=0..7) = K[row][slot ^ (row&7)].
__device__ __forceinline__ void stageK(const unsigned short* __restrict__ Kbase, int t0,
                                       int tid, unsigned short* lbuf) {
  const int w = tid >> 6;
  const int r = tid >> 3;                       // 0..31
  const int c = (tid & 7) ^ (r & 7);            // inverse-swizzled source chunk
  const char* src = (const char*)Kbase + ((size_t)(t0 + r) << 7) + (c << 4);
  char* ldst = (char*)lbuf + (w << 10);         // wave-uniform; HW adds lane*16
  gload16(src, ldst);
  gload16(src + (32 << 7), ldst + 4096);        // rows 32..63, same swizzle
}

// 64 q-rows per wave: K-fragments read once from LDS feed 4 row-blocks.
// Diagonal self-exclusion folded in (bit-exact r1-r5): zero the diag
// element of fragment (rb==f) instead of a separate correction pass.
__device__ __forceinline__ void computeTile64(const unsigned short* lbuf, const short8v q[4][2],
                                              f32x4 sp[4], bool isD, int l15, int lhi) {
  short8v kf[4][2];
  const int sw = l15 & 7;
#pragma unroll
  for (int f = 0; f < 4; ++f) {
    const char* p = (const char*)lbuf + ((f * 16 + l15) << 7);
    kf[f][0] = *(const short8v*)(p + ((lhi ^ sw) << 4));
    kf[f][1] = *(const short8v*)(p + (((lhi + 4) ^ sw) << 4));
  }
#pragma unroll
  for (int rb = 0; rb < 4; ++rb) {
    f32x4 acc[4] = {};
#pragma unroll
    for (int f = 0; f < 4; ++f) {
      acc[f] = __builtin_amdgcn_mfma_f32_16x16x32_bf16(q[rb][0], kf[f][0], acc[f], 0, 0, 0);
      acc[f] = __builtin_amdgcn_mfma_f32_16x16x32_bf16(q[rb][1], kf[f][1], acc[f], 0, 0, 0);
    }
#pragma unroll
    for (int f = 0; f < 4; ++f) {
      f32x4 e;
#pragma unroll
      for (int r = 0; r < 4; ++r) e[r] = __builtin_amdgcn_exp2f(acc[f][r]);
      if (isD && f == rb) {
#pragma unroll
        for (int r = 0; r < 4; ++r)
          if (l15 == lhi * 4 + r) e[r] = 0.f;
      }
      sp[rb] += e;                        // v_pk_add_f32 x2
    }
  }
}

// LSE row sums. 4 waves x 64 rows = 256 rows/block; t-range split in 4
// (8 tiles/block). 3-buffer rotation, one barrier per tile (proven best
// operating point across r0-r5: deeper pipelines/LDS-free/reg-dbuf all
// regress or tie; lse plateaus at ~45us, exp2-VALU dominated).
__global__ __launch_bounds__(256) void lse_kernel(const unsigned short* __restrict__ Qb,
                                                  const unsigned short* __restrict__ Kb,
                                                  float* __restrict__ rowsum) {
  __shared__ __align__(16) unsigned short lK[3][4096];   // 3 x 8 KB
  const int L = blockIdx.x + 8 * (blockIdx.y + 12 * blockIdx.z);  // 0..1535
  const int xcd = L & 7, j = L >> 3;      // hw round-robins wgid%8 -> XCD
  const int split = j & 3;
  const int st = (j >> 2) & 7;
  const int g = xcd + 8 * (j >> 5);       // (b,h) group, 0..47
  const int h = g % H_, b = g / H_;

  const int tid = threadIdx.x;
  const int wid = tid >> 6, lane = tid & 63;
  const int l15 = lane & 15, lhi = lane >> 4;
  const size_t hb = ((size_t)b * H_ + h) * S_;
  const unsigned short* Qbase = Qb + hb * D_;
  const unsigned short* Kbase = Kb + hb * D_;
  const int s0 = st * 256 + wid * 64;     // 64 rows per wave
  const int tb = split * 512;             // 8 tiles of 64

  short8v q[4][2];
#pragma unroll
  for (int rb = 0; rb < 4; ++rb) {
    const unsigned short* qr = Qbase + (size_t)(s0 + rb * 16 + l15) * D_ + lhi * 8;
    q[rb][0] = *(const short8v*)qr;
    q[rb][1] = *(const short8v*)(qr + 32);
  }

  // tile index (within this split's 8 tiles) holding this wave's diagonal
  const int dtile = ((s0 >> 9) == split) ? ((s0 - tb) >> 6) : -1;

  f32x4 sp[4] = {};                       // sp[rb][r] row partial sums
  stageK(Kbase, tb, tid, lK[0]);
  stageK(Kbase, tb + 64, tid, lK[1]);
  int bi = 0;
#pragma unroll 1
  for (int i = 0; i < 7; ++i) {
    VM2;                                   // own tile-i loads done (only i+1 in flight)
    BAR;                                   // tile-i fully visible; compute(i-1) done
    if (i < 6) {
      int bs_ = bi + 2; if (bs_ >= 3) bs_ -= 3;
      stageK(Kbase, tb + (i + 2) * 64, tid, lK[bs_]);
    }
    computeTile64(lK[bi], q, sp, i == dtile, l15, lhi);
    if (++bi == 3) bi = 0;
  }
  VM0; BAR;
  computeTile64(lK[bi], q, sp, 7 == dtile, l15, lhi);

#pragma unroll
  for (int rb = 0; rb < 4; ++rb)
#pragma unroll
    for (int r = 0; r < 4; ++r) {
      float s = sp[rb][r];
#pragma unroll
      for (int off = 1; off < 16; off <<= 1) s += __shfl_xor(s, off, 64);
      if (l15 == 0)
        rowsum[(size_t)split * NROWS + hb + s0 + rb * 16 + lhi * 4 + r] = s;
    }
}

__global__ __launch_bounds__(256) void finish1_kernel(const float* __restrict__ rowsum,
                                                      const float* __restrict__ beta,
                                                      float* __restrict__ partial) {
  int row = blockIdx.x * 256 + threadIdx.x;
  float s = (rowsum[row] + rowsum[NROWS + row]) +
            (rowsum[2 * NROWS + row] + rowsum[3 * NROWS + row]);
  int h = (row >> 11) % H_;
  float c = __builtin_amdgcn_logf(s) * LN2 / beta[h];   // v_log_f32 = log2
#pragma unroll
  for (int off = 1; off < 64; off <<= 1) c += __shfl_xor(c, off, 64);
  __shared__ float wsum[4];
  int wid = threadIdx.x >> 6;
  if ((threadIdx.x & 63) == 0) wsum[wid] = c;
  __syncthreads();
  if (threadIdx.x == 0) partial[blockIdx.x] = wsum[0] + wsum[1] + wsum[2] + wsum[3];
}

__global__ __launch_bounds__(256) void finish2_kernel(const float* __restrict__ partial, int n,
                                                      float* __restrict__ out) {
  float s = 0.f;
  for (int i = threadIdx.x; i < n; i += 256) s += partial[i];
#pragma unroll
  for (int off = 1; off < 64; off <<= 1) s += __shfl_xor(s, off, 64);
  __shared__ float wsum[4];
  int wid = threadIdx.x >> 6;
  if ((threadIdx.x & 63) == 0) wsum[wid] = s;
  __syncthreads();
  if (threadIdx.x == 0) out[0] = -(wsum[0] + wsum[1] + wsum[2] + wsum[3]);
}

extern "C" void kernel_launch(void* const* d_in, const int* in_sizes, int n_in,
                              void* d_out, int out_size, void* d_ws, size_t ws_size,
                              hipStream_t stream) {
  const float* x    = (const float*)d_in[0];
  const float* wq   = (const float*)d_in[1];
  const float* wk   = (const float*)d_in[2];
  const float* beta = (const float*)d_in[3];

  char* ws = (char*)d_ws;
  const size_t wb_bytes = (size_t)2 * H_ * D_ * E_ * 2;    //  2,359,296
  const size_t qk_bytes = (size_t)B_ * H_ * S_ * D_ * 2;   // 12,582,912
  const size_t rs_bytes = (size_t)4 * NROWS * 4;           //   1,572,864
  unsigned short* wb = (unsigned short*)ws;
  unsigned short* Qb = (unsigned short*)(ws + wb_bytes);
  unsigned short* Kb = (unsigned short*)(ws + wb_bytes + qk_bytes);
  float* rowsum      = (float*)(ws + wb_bytes + 2 * qk_bytes);
  float* partial     = (float*)(ws + wb_bytes + 2 * qk_bytes + rs_bytes);

  int nw4 = (H_ * D_ * E_) / 4;
  cvt_w_kernel<<<(2 * nw4 + 255) / 256, 256, 0, stream>>>((const float4*)wq, (const float4*)wk,
                                                          beta, (ushort4*)wb, nw4);

  dim3 pgrid((B_ * S_) / 128, (2 * H_ * D_) / 128);   // 64 x 12
  proj_kernel<<<pgrid, 256, 0, stream>>>(x, wb, Qb, Kb);

  dim3 lgrid(S_ / 256, H_, B_ * 4);                    // 8 x 12 x 16 = 1536 blocks
  lse_kernel<<<lgrid, 256, 0, stream>>>(Qb, Kb, rowsum);

  finish1_kernel<<<NROWS / 256, 256, 0, stream>>>(rowsum, beta, partial);
  finish2_kernel<<<1, 256, 0, stream>>>(partial, NROWS / 256, (float*)d_out);
}